// Round 12
// baseline (449.755 us; speedup 1.0000x reference)
//
#include <hip/hip_runtime.h>

// VposeFiled_Vjmlp: RFF encode + 80-group weight-norm MLP chain (480->512->512->256->6)
// R12: prep_x FUSED into mlp staging (RFF + transpose-gather computed in-block):
//      kills the 157MB Xg write+read round-trip and the ~90us prep_x dispatch;
//      mlp was at 7.5% HBM BW -> pf reads overlap with MFMA. R11's K-loop kept:
//      32x32x16 MFMA, SMLP=520 (2-way), depth-3 named B prefetch, setprio.

typedef __attribute__((ext_vector_type(8)))  short short8;
typedef __attribute__((ext_vector_type(4)))  float f32x4;
typedef __attribute__((ext_vector_type(16))) float f32x16;

#define VJ    80
#define FS    480
#define HD2   512
#define HD    256
#define BATCH 2048
#define SMLP  520   // stride ushorts: 260 dw ≡ 4 (mod 32) -> ~2-way on 32-row b128 reads

static __device__ __forceinline__ unsigned short f2bf(float f) {
  unsigned int u = __builtin_bit_cast(unsigned int, f);
  u += 0x7FFFu + ((u >> 16) & 1u);          // round-to-nearest-even
  return (unsigned short)(u >> 16);
}

// ---------------------------------------------------------------------------
// Weight prep (single launch, 512 thr). Blocks: [0,1280) W0, [1280,2560) W1,
// [2560,3200) W2 (32-row tiles, 32x32 frag pack), [3200,3280) W3 (per-group,
// 16x16 frag pack with cols padded 6->16).
// 32x32 frag(nt,ks) = 512 ushorts: lane l elem j = W[nt*32+(l&31)][ks*16+(l>>5)*8+j]
// ---------------------------------------------------------------------------
template<int K, int RPG>
static __device__ __forceinline__ void wfrag32_body(
    int blk, const float* __restrict__ v, const float* __restrict__ gain,
    unsigned short* __restrict__ dst, float* sV, float* sScale) {
  constexpr int KS = K / 16;
  constexpr int KP = K + 4;
  const int t  = threadIdx.x;
  const int n0 = blk * 32;
  const int g  = n0 / RPG;
  const int nt = (n0 % RPG) >> 5;

  const f32x4* v4 = (const f32x4*)(v + (size_t)n0 * K);
  for (int idx = t; idx < 32 * K / 4; idx += 512) {
    int row = idx / (K / 4), rem = idx - row * (K / 4);
    *(f32x4*)&sV[row * KP + rem * 4] = v4[idx];
  }
  __syncthreads();

  const int wave = t >> 6, lane = t & 63;
  for (int r = wave; r < 32; r += 8) {
    float s = 0.f;
    for (int k = lane; k < K; k += 64) { float x = sV[r * KP + k]; s += x * x; }
    #pragma unroll
    for (int off = 32; off > 0; off >>= 1) s += __shfl_down(s, off);
    if (lane == 0) sScale[r] = gain[n0 + r] / sqrtf(s);
  }
  __syncthreads();

  unsigned short* db = dst + (size_t)g * RPG * K + (size_t)nt * KS * 512;
  for (int o = t; o < KS * 64; o += 512) {
    int ks = o >> 6, l = o & 63;
    int nl = l & 31, k0 = ks * 16 + ((l >> 5) << 3);
    float sc = sScale[nl];
    short8 pk;
    #pragma unroll
    for (int j = 0; j < 8; ++j) pk[j] = (short)f2bf(sV[nl * KP + k0 + j] * sc);
    *(short8*)&db[(size_t)ks * 512 + l * 8] = pk;
  }
}

// W3 per-group: 6 rows, K=256 -> 8 frags (16x16x32), cols padded to 16 w/ zeros.
static __device__ __forceinline__ void w3frag_body(
    int gidx, const float* __restrict__ v3, const float* __restrict__ g3,
    unsigned short* __restrict__ W3f, float* sV, float* sScale) {
  const int t = threadIdx.x;
  const f32x4* v4 = (const f32x4*)(v3 + (size_t)gidx * 6 * 256);
  if (t < 384) {
    int row = t >> 6, rem = t & 63;
    *(f32x4*)&sV[row * 260 + rem * 4] = v4[t];
  }
  __syncthreads();
  const int wave = t >> 6, lane = t & 63;
  if (wave < 6) {
    float s = 0.f;
    #pragma unroll
    for (int k = 0; k < 4; ++k) { float x = sV[wave * 260 + lane + k * 64]; s += x * x; }
    #pragma unroll
    for (int off = 32; off > 0; off >>= 1) s += __shfl_down(s, off);
    if (lane == 0) sScale[wave] = g3[gidx * 6 + wave] / sqrtf(s);
  }
  __syncthreads();
  {
    int ks = t >> 6, l = t & 63;
    int c = l & 15, k0 = ks * 32 + ((l >> 4) << 3);
    short8 pk;
    #pragma unroll
    for (int j = 0; j < 8; ++j)
      pk[j] = (c < 6) ? (short)f2bf(sV[c * 260 + k0 + j] * sScale[c]) : (short)0;
    *(short8*)&W3f[(size_t)gidx * 4096 + (size_t)ks * 512 + l * 8] = pk;
  }
}

__global__ void __launch_bounds__(512)
prep_weights(const float* __restrict__ v0, const float* __restrict__ g0,
             const float* __restrict__ v1, const float* __restrict__ g1,
             const float* __restrict__ v2, const float* __restrict__ g2,
             const float* __restrict__ v3, const float* __restrict__ g3,
             unsigned short* __restrict__ W0, unsigned short* __restrict__ W1,
             unsigned short* __restrict__ W2, unsigned short* __restrict__ W3f) {
  __shared__ float sV[32 * 516];
  __shared__ float sScale[32];
  const int b = blockIdx.x;
  if      (b < 1280) wfrag32_body<480, 512>(b,        v0, g0, W0, sV, sScale);
  else if (b < 2560) wfrag32_body<512, 512>(b - 1280, v1, g1, W1, sV, sScale);
  else if (b < 3200) wfrag32_body<512, 256>(b - 2560, v2, g2, W2, sV, sScale);
  else               w3frag_body(b - 3200, v3, g3, W3f, sV, sScale);
}

// ---------------------------------------------------------------------------
// mlp: fused RFF-encode + 4-layer grouped MLP. M=64 rows/block, 8 waves,
// in-place LDS [64][SMLP] = 65 KB -> 2 blocks/CU.
// Stage: s[r][cl*80+n] = bf16( pf[b,n,g*6+cl] + cos/sin(2pi * qp[b,n,:]·B[:,k]) )
//   with k = g*6+cl (mod 240); group is all-cos (g<40) or all-sin (g>=40).
// K-loop: 32x32x16 MFMA, depth-3 named B prefetch issued before MFMA cluster.
// ---------------------------------------------------------------------------
#define MLP_STEP32(ksv, BB)                                                   \
  {                                                                           \
    const int ksc = (ksv);                                                    \
    short8 a0 = *(const short8*)(aB + ksc * 16);                              \
    short8 a1 = *(const short8*)(aB + 32 * SMLP + ksc * 16);                  \
    short8 p0, p1;                                                            \
    const bool pf_ok = (ksc + 3 < KS);                                        \
    if (pf_ok) {                                                              \
      p0 = *(const short8*)(wB + ((size_t)0 * KS + ksc + 3) * 512);           \
      if (NT > 1) p1 = *(const short8*)(wB + ((size_t)1 * KS + ksc + 3) * 512); \
    }                                                                         \
    __builtin_amdgcn_s_setprio(1);                                            \
    _Pragma("unroll")                                                         \
    for (int nt = 0; nt < NT; ++nt)                                           \
      acc[0][nt] = __builtin_amdgcn_mfma_f32_32x32x16_bf16(a0, BB[nt], acc[0][nt], 0, 0, 0); \
    _Pragma("unroll")                                                         \
    for (int nt = 0; nt < NT; ++nt)                                           \
      acc[1][nt] = __builtin_amdgcn_mfma_f32_32x32x16_bf16(a1, BB[nt], acc[1][nt], 0, 0, 0); \
    __builtin_amdgcn_s_setprio(0);                                            \
    if (pf_ok) {                                                              \
      BB[0] = p0;                                                             \
      if (NT > 1) BB[1] = p1;                                                 \
    }                                                                         \
  }

template<int K, int N, bool ACT>
static __device__ __forceinline__ void run_layer32(
    unsigned short* __restrict__ s,
    const unsigned short* __restrict__ Wf, const float* __restrict__ bias,
    int wn, int lane) {
  constexpr int NT = N / 256;              // n-tiles per wave (2 or 1)
  constexpr int KS = K / 16;               // k16 steps (30 or 32)
  const int nbase = wn * (N / 8);
  const int lr = lane & 31, lh = lane >> 5;

  f32x16 acc[2][NT];
  #pragma unroll
  for (int mt = 0; mt < 2; ++mt)
    #pragma unroll
    for (int nt = 0; nt < NT; ++nt)
      #pragma unroll
      for (int r = 0; r < 16; ++r) acc[mt][nt][r] = 0.f;

  const unsigned short* aB = s + lr * SMLP + lh * 8;
  const unsigned short* wB = Wf + (size_t)(wn * NT) * KS * 512 + lane * 8;

  short8 bb0[NT], bb1[NT], bb2[NT];
  #pragma unroll
  for (int nt = 0; nt < NT; ++nt) bb0[nt] = *(const short8*)(wB + ((size_t)nt * KS    ) * 512);
  #pragma unroll
  for (int nt = 0; nt < NT; ++nt) bb1[nt] = *(const short8*)(wB + ((size_t)nt * KS + 1) * 512);
  #pragma unroll
  for (int nt = 0; nt < NT; ++nt) bb2[nt] = *(const short8*)(wB + ((size_t)nt * KS + 2) * 512);

  #pragma unroll
  for (int ks3 = 0; ks3 < KS / 3; ++ks3) {
    MLP_STEP32(3 * ks3,     bb0);
    MLP_STEP32(3 * ks3 + 1, bb1);
    MLP_STEP32(3 * ks3 + 2, bb2);
  }
  if (KS % 3 == 2) {                        // KS=32: two tail steps
    MLP_STEP32(KS - 2, bb0);
    MLP_STEP32(KS - 1, bb1);
  }

  float bv[NT];                             // bias loaded AFTER K-loop
  #pragma unroll
  for (int nt = 0; nt < NT; ++nt) bv[nt] = bias[nbase + nt * 32 + lr];

  __syncthreads();   // all waves done READING s
  #pragma unroll
  for (int mt = 0; mt < 2; ++mt)
    #pragma unroll
    for (int nt = 0; nt < NT; ++nt)
      #pragma unroll
      for (int r = 0; r < 16; ++r) {
        float val = acc[mt][nt][r] + bv[nt];
        if (ACT) val = (val >= 0.f) ? val : 0.01f * val;
        const int row = mt * 32 + (r & 3) + 8 * (r >> 2) + 4 * lh;
        s[row * SMLP + (nbase + nt * 32 + lr)] = f2bf(val);
      }
  __syncthreads();   // writes visible before next layer reads
}

__global__ void __launch_bounds__(512, 4)
mlp_kernel(const float* __restrict__ qp, const float* __restrict__ pf,
           const float* __restrict__ Brff,
           const unsigned short* __restrict__ W0, const unsigned short* __restrict__ W1,
           const unsigned short* __restrict__ W2, const unsigned short* __restrict__ W3f,
           const float* __restrict__ b0, const float* __restrict__ b1,
           const float* __restrict__ b2, const float* __restrict__ b3,
           float* __restrict__ out) {
  __shared__ unsigned short s[64 * SMLP];   // 65 KB -> 2 blocks/CU

  // XCD swizzle: bid%8 = XCD; each XCD walks its 10 groups' 32 tiles.
  const int bid   = blockIdx.x;
  const int xcd   = bid & 7;
  const int local = bid >> 3;                // 0..319
  const int g     = xcd * 10 + (local >> 5);
  const int tile  = local & 31;
  const int m0    = tile * 64;

  const int tid  = threadIdx.x, lane = tid & 63;
  const int wn   = tid >> 6;                 // col strip 0..7

  // ---- fused RFF stage: s[r][cl*80+n] = pf + cos/sin(2pi qp·B) ----
  // channels c = g*6+cl are all <240 (cos, k=c) for g<40, else all sin (k=c-240)
  {
    const int kbase = (g < 40) ? g * 6 : g * 6 - 240;
    const bool ucos = (g < 40);
    float Bx[6], By[6], Bz[6];
    #pragma unroll
    for (int j = 0; j < 6; ++j) {
      Bx[j] = Brff[kbase + j];
      By[j] = Brff[240 + kbase + j];
      Bz[j] = Brff[480 + kbase + j];
    }
    for (int p = tid; p < 64 * 80; p += 512) {
      int r = p / 80, n = p - r * 80;        // n minor -> coalesced qp reads
      const size_t brow = (size_t)(m0 + r);
      const float* qpp = qp + brow * 240 + n * 3;
      const float qx = qpp[0], qy = qpp[1], qz = qpp[2];
      const float* pfp = pf + (brow * 80 + n) * 480 + g * 6;
      unsigned short* sr = s + r * SMLP + n;
      #pragma unroll
      for (int j = 0; j < 6; ++j) {
        float d = qx * Bx[j] + qy * By[j] + qz * Bz[j];
        // v_sin/v_cos take revolutions: sin(2*pi*d) == v_sin(d)
        float f = ucos ? __builtin_amdgcn_cosf(d) : __builtin_amdgcn_sinf(d);
        sr[j * 80] = f2bf(pfp[j] + f);
      }
    }
  }
  __syncthreads();

  run_layer32<480, 512, true>(s, W0 + (size_t)g * 512 * 480, b0 + g * 512, wn, lane);
  run_layer32<512, 512, true>(s, W1 + (size_t)g * 512 * 512, b1 + g * 512, wn, lane);
  run_layer32<512, 256, true>(s, W2 + (size_t)g * 256 * 512, b2 + g * 256, wn, lane);

  // layer 4 via MFMA: [64x256] @ [256x16(pad 6)] ; waves 0-3 each own 16 rows.
  if (wn < 4) {
    const int lr = lane & 15, lh = lane >> 4;
    const unsigned short* aB4 = s + (wn * 16 + lr) * SMLP + lh * 8;
    const unsigned short* w3  = W3f + (size_t)g * 4096 + lane * 8;
    f32x4 a4 = (f32x4){0.f, 0.f, 0.f, 0.f};
    #pragma unroll
    for (int kk = 0; kk < 8; ++kk) {
      short8 av  = *(const short8*)(aB4 + kk * 32);
      short8 wv8 = *(const short8*)(w3 + (size_t)kk * 512);
      a4 = __builtin_amdgcn_mfma_f32_16x16x32_bf16(av, wv8, a4, 0, 0, 0);
    }
    const int col = lane & 15;
    if (col < 6) {
      const float bias3 = b3[g * 6 + col];
      #pragma unroll
      for (int r = 0; r < 4; ++r)
        out[((size_t)(m0 + wn * 16 + lh * 4 + r) * VJ + g) * 6 + col] = a4[r] + bias3;
    }
  }
}

// ---------------------------------------------------------------------------
extern "C" void kernel_launch(void* const* d_in, const int* in_sizes, int n_in,
                              void* d_out, int out_size, void* d_ws, size_t ws_size,
                              hipStream_t stream) {
  const float* qp   = (const float*)d_in[0];
  const float* pf   = (const float*)d_in[1];
  const float* Brff = (const float*)d_in[2];
  const float* v0 = (const float*)d_in[3];  const float* g0 = (const float*)d_in[4];  const float* b0 = (const float*)d_in[5];
  const float* v1 = (const float*)d_in[6];  const float* g1 = (const float*)d_in[7];  const float* b1 = (const float*)d_in[8];
  const float* v2 = (const float*)d_in[9];  const float* g2 = (const float*)d_in[10]; const float* b2 = (const float*)d_in[11];
  const float* v3 = (const float*)d_in[12]; const float* g3 = (const float*)d_in[13]; const float* b3 = (const float*)d_in[14];

  unsigned short* W0  = (unsigned short*)d_ws;                // 32x32 frag layout
  unsigned short* W1  = W0 + (size_t)VJ * HD2 * FS;
  unsigned short* W2  = W1 + (size_t)VJ * HD2 * HD2;
  unsigned short* W3f = W2 + (size_t)VJ * HD  * HD2;          // 16x16 frags, 6->16 pad

  prep_weights<<<dim3(3280), dim3(512), 0, stream>>>(v0, g0, v1, g1, v2, g2, v3, g3,
                                                     W0, W1, W2, W3f);
  mlp_kernel<<<dim3(VJ * 32), dim3(512), 0, stream>>>(qp, pf, Brff, W0, W1, W2, W3f,
                                                      b0, b1, b2, b3, (float*)d_out);
}

// Round 13
// 393.598 us; speedup vs baseline: 1.1427x; 1.1427x over previous
//
#include <hip/hip_runtime.h>

// VposeFiled_Vjmlp: RFF encode + 80-group weight-norm MLP chain (480->512->512->256->6)
// R13: REVERT R12's fused staging (it was pure HBM overfetch: 1.05GB, 24B-of-64B
//      lines). mlp = R11 exactly (237us, MfmaUtil 41%). NEW: prep_x and
//      prep_weights merged into ONE interleaved launch (3:2 quintets) — both are
//      near-BW-bound and independent; serial was ~160us, merged target ~135us.

typedef __attribute__((ext_vector_type(8)))  short short8;
typedef __attribute__((ext_vector_type(4)))  float f32x4;
typedef __attribute__((ext_vector_type(16))) float f32x16;
typedef __attribute__((ext_vector_type(2)))  unsigned int uint2v;

#define VJ    80
#define FS    480
#define HD2   512
#define HD    256
#define BATCH 2048
#define SMLP  520   // stride ushorts: 260 dw ≡ 4 (mod 32) -> ~2-way on 32-row b128 reads

static __device__ __forceinline__ unsigned short f2bf(float f) {
  unsigned int u = __builtin_bit_cast(unsigned int, f);
  u += 0x7FFFu + ((u >> 16) & 1u);          // round-to-nearest-even
  return (unsigned short)(u >> 16);
}

// ---------------------------------------------------------------------------
// Merged prep (1024 thr). Quintets: 3 weight-blocks + 2 prep_x-blocks.
// Weight blocks: [0,1280) W0, [1280,2560) W1, [2560,3200) W2 (32x32 frag pack),
// [3200,3280) W3 (16x16 frags, cols padded 6->16).
// 32x32 frag(nt,ks) = 512 ushorts: lane l elem j = W[nt*32+(l&31)][ks*16+(l>>5)*8+j]
// ---------------------------------------------------------------------------
template<int K, int RPG>
static __device__ __forceinline__ void wfrag32_body(
    int blk, const float* __restrict__ v, const float* __restrict__ gain,
    unsigned short* __restrict__ dst, float* sV, float* sScale) {
  constexpr int KS = K / 16;
  constexpr int KP = K + 4;
  const int t  = threadIdx.x;               // 0..1023
  const int n0 = blk * 32;
  const int g  = n0 / RPG;
  const int nt = (n0 % RPG) >> 5;

  const f32x4* v4 = (const f32x4*)(v + (size_t)n0 * K);
  for (int idx = t; idx < 32 * K / 4; idx += 1024) {
    int row = idx / (K / 4), rem = idx - row * (K / 4);
    *(f32x4*)&sV[row * KP + rem * 4] = v4[idx];
  }
  __syncthreads();

  const int wave = t >> 6, lane = t & 63;   // 16 waves
  for (int r = wave; r < 32; r += 16) {
    float s = 0.f;
    for (int k = lane; k < K; k += 64) { float x = sV[r * KP + k]; s += x * x; }
    #pragma unroll
    for (int off = 32; off > 0; off >>= 1) s += __shfl_down(s, off);
    if (lane == 0) sScale[r] = gain[n0 + r] / sqrtf(s);
  }
  __syncthreads();

  unsigned short* db = dst + (size_t)g * RPG * K + (size_t)nt * KS * 512;
  for (int o = t; o < KS * 64; o += 1024) {
    int ks = o >> 6, l = o & 63;
    int nl = l & 31, k0 = ks * 16 + ((l >> 5) << 3);
    float sc = sScale[nl];
    short8 pk;
    #pragma unroll
    for (int j = 0; j < 8; ++j) pk[j] = (short)f2bf(sV[nl * KP + k0 + j] * sc);
    *(short8*)&db[(size_t)ks * 512 + l * 8] = pk;
  }
}

// W3 per-group: 6 rows, K=256 -> 8 frags (16x16x32), cols padded to 16 w/ zeros.
static __device__ __forceinline__ void w3frag_body(
    int gidx, const float* __restrict__ v3, const float* __restrict__ g3,
    unsigned short* __restrict__ W3f, float* sV, float* sScale) {
  const int t = threadIdx.x;
  const f32x4* v4 = (const f32x4*)(v3 + (size_t)gidx * 6 * 256);
  if (t < 384) {
    int row = t >> 6, rem = t & 63;
    *(f32x4*)&sV[row * 260 + rem * 4] = v4[t];
  }
  __syncthreads();
  const int wave = t >> 6, lane = t & 63;
  if (wave < 6) {
    float s = 0.f;
    #pragma unroll
    for (int k = 0; k < 4; ++k) { float x = sV[wave * 260 + lane + k * 64]; s += x * x; }
    #pragma unroll
    for (int off = 32; off > 0; off >>= 1) s += __shfl_down(s, off);
    if (lane == 0) sScale[wave] = g3[gidx * 6 + wave] / sqrtf(s);
  }
  __syncthreads();
  if (t < 512) {
    int ks = t >> 6, l = t & 63;
    int c = l & 15, k0 = ks * 32 + ((l >> 4) << 3);
    short8 pk;
    #pragma unroll
    for (int j = 0; j < 8; ++j)
      pk[j] = (c < 6) ? (short)f2bf(sV[c * 260 + k0 + j] * sScale[c]) : (short)0;
    *(short8*)&W3f[(size_t)gidx * 4096 + (size_t)ks * 512 + l * 8] = pk;
  }
}

// prep_x body (identical math to R11): x = pf + [cos|sin](2pi qp·B), transpose-
// gather to Xg[g][b][i], i = cl*80 + n, c = g*6 + cl.
static __device__ __forceinline__ void prep_x_body(
    int b, const float* __restrict__ qp, const float* __restrict__ pf,
    const float* __restrict__ Brff, unsigned short* __restrict__ Xg,
    float* sB, float* sQ, unsigned short* sX) {
  const int t = threadIdx.x;
  if (t < 720) sB[t] = Brff[t];
  if (t < 240) sQ[t] = qp[(size_t)b * 240 + t];
  __syncthreads();
  const float* pfb = pf + (size_t)b * 38400;
  #pragma unroll 2
  for (int idx = t; idx < 19200; idx += 1024) {
    int n2 = idx / 480;
    int c  = idx - n2 * 480;
    int n  = n2 * 2;
    int k  = (c < 240) ? c : c - 240;
    float bx = sB[k], by = sB[240 + k], bz = sB[480 + k];
    float d0 = sQ[n*3]   * bx + sQ[n*3+1] * by + sQ[n*3+2] * bz;
    float d1 = sQ[n*3+3] * bx + sQ[n*3+4] * by + sQ[n*3+5] * bz;
    // v_sin/v_cos take revolutions: sin(2*pi*d) == v_sin(d)
    float f0 = (c < 240) ? __builtin_amdgcn_cosf(d0) : __builtin_amdgcn_sinf(d0);
    float f1 = (c < 240) ? __builtin_amdgcn_cosf(d1) : __builtin_amdgcn_sinf(d1);
    unsigned int w = (unsigned int)f2bf(pfb[n * 480 + c] + f0)
                   | ((unsigned int)f2bf(pfb[(n + 1) * 480 + c] + f1) << 16);
    *(unsigned int*)&sX[c * 82 + n] = w;
  }
  __syncthreads();
  for (int idx4 = t; idx4 < 9600; idx4 += 1024) {
    int g  = idx4 / 120;
    int i4 = idx4 - g * 120;
    int i  = i4 * 4;
    int cl = i / 80;
    int n  = i - cl * 80;
    const unsigned int* p = (const unsigned int*)&sX[(g * 6 + cl) * 82 + n];
    uint2v val = { p[0], p[1] };
    *(uint2v*)(Xg + ((size_t)g * BATCH + b) * 480 + i) = val;
  }
}

__global__ void __launch_bounds__(1024)
prep_all(const float* __restrict__ qp, const float* __restrict__ pf,
         const float* __restrict__ Brff,
         const float* __restrict__ v0, const float* __restrict__ g0,
         const float* __restrict__ v1, const float* __restrict__ g1,
         const float* __restrict__ v2, const float* __restrict__ g2,
         const float* __restrict__ v3, const float* __restrict__ g3,
         unsigned short* __restrict__ W0, unsigned short* __restrict__ W1,
         unsigned short* __restrict__ W2, unsigned short* __restrict__ W3f,
         unsigned short* __restrict__ Xg) {
  // LDS union: prep_x needs 720f + 240f + 480*82 us = 82.5 KB; weights 66.2 KB.
  __shared__ float sMem[960];                      // sB(720) + sQ(240)
  __shared__ unsigned short sBig[480 * 82];        // sX  / aliases sV+sScale
  const int bid = blockIdx.x;
  const int q = bid / 5, r = bid - q * 5;
  if (r < 3) {
    const int wb = q * 3 + r;
    float* sV = (float*)sBig;                      // 32*516 f = 66 KB <= 78.7 KB
    float* sScale = sMem;                          // 32 floats
    if      (wb < 1280) wfrag32_body<480, 512>(wb,        v0, g0, W0, sV, sScale);
    else if (wb < 2560) wfrag32_body<512, 512>(wb - 1280, v1, g1, W1, sV, sScale);
    else if (wb < 3200) wfrag32_body<512, 256>(wb - 2560, v2, g2, W2, sV, sScale);
    else if (wb < 3280) w3frag_body(wb - 3200, v3, g3, W3f, sV, sScale);
  } else {
    const int pb = q * 2 + (r - 3);
    if (pb < BATCH)
      prep_x_body(pb, qp, pf, Brff, Xg, sMem, sMem + 720, sBig);
  }
}

// ---------------------------------------------------------------------------
// mlp: R11 exactly. M=64 rows/block, 8 waves, in-place LDS [64][SMLP] = 65 KB
// -> 2 blocks/CU. 32x32x16 MFMA; wave wn owns cols [wn*64,+64) as NT n-tiles.
// acc f32x16[2][NT] (64 AGPR); depth-3 named B prefetch issued before MFMAs.
// ---------------------------------------------------------------------------
#define MLP_STEP32(ksv, BB)                                                   \
  {                                                                           \
    const int ksc = (ksv);                                                    \
    short8 a0 = *(const short8*)(aB + ksc * 16);                              \
    short8 a1 = *(const short8*)(aB + 32 * SMLP + ksc * 16);                  \
    short8 p0, p1;                                                            \
    const bool pf_ok = (ksc + 3 < KS);                                        \
    if (pf_ok) {                                                              \
      p0 = *(const short8*)(wB + ((size_t)0 * KS + ksc + 3) * 512);           \
      if (NT > 1) p1 = *(const short8*)(wB + ((size_t)1 * KS + ksc + 3) * 512); \
    }                                                                         \
    __builtin_amdgcn_s_setprio(1);                                            \
    _Pragma("unroll")                                                         \
    for (int nt = 0; nt < NT; ++nt)                                           \
      acc[0][nt] = __builtin_amdgcn_mfma_f32_32x32x16_bf16(a0, BB[nt], acc[0][nt], 0, 0, 0); \
    _Pragma("unroll")                                                         \
    for (int nt = 0; nt < NT; ++nt)                                           \
      acc[1][nt] = __builtin_amdgcn_mfma_f32_32x32x16_bf16(a1, BB[nt], acc[1][nt], 0, 0, 0); \
    __builtin_amdgcn_s_setprio(0);                                            \
    if (pf_ok) {                                                              \
      BB[0] = p0;                                                             \
      if (NT > 1) BB[1] = p1;                                                 \
    }                                                                         \
  }

template<int K, int N, bool ACT>
static __device__ __forceinline__ void run_layer32(
    unsigned short* __restrict__ s,
    const unsigned short* __restrict__ Wf, const float* __restrict__ bias,
    int wn, int lane) {
  constexpr int NT = N / 256;              // n-tiles per wave (2 or 1)
  constexpr int KS = K / 16;               // k16 steps (30 or 32)
  const int nbase = wn * (N / 8);
  const int lr = lane & 31, lh = lane >> 5;

  f32x16 acc[2][NT];
  #pragma unroll
  for (int mt = 0; mt < 2; ++mt)
    #pragma unroll
    for (int nt = 0; nt < NT; ++nt)
      #pragma unroll
      for (int r = 0; r < 16; ++r) acc[mt][nt][r] = 0.f;

  const unsigned short* aB = s + lr * SMLP + lh * 8;
  const unsigned short* wB = Wf + (size_t)(wn * NT) * KS * 512 + lane * 8;

  short8 bb0[NT], bb1[NT], bb2[NT];
  #pragma unroll
  for (int nt = 0; nt < NT; ++nt) bb0[nt] = *(const short8*)(wB + ((size_t)nt * KS    ) * 512);
  #pragma unroll
  for (int nt = 0; nt < NT; ++nt) bb1[nt] = *(const short8*)(wB + ((size_t)nt * KS + 1) * 512);
  #pragma unroll
  for (int nt = 0; nt < NT; ++nt) bb2[nt] = *(const short8*)(wB + ((size_t)nt * KS + 2) * 512);

  #pragma unroll
  for (int ks3 = 0; ks3 < KS / 3; ++ks3) {
    MLP_STEP32(3 * ks3,     bb0);
    MLP_STEP32(3 * ks3 + 1, bb1);
    MLP_STEP32(3 * ks3 + 2, bb2);
  }
  if (KS % 3 == 2) {                        // KS=32: two tail steps
    MLP_STEP32(KS - 2, bb0);
    MLP_STEP32(KS - 1, bb1);
  }

  float bv[NT];                             // bias loaded AFTER K-loop
  #pragma unroll
  for (int nt = 0; nt < NT; ++nt) bv[nt] = bias[nbase + nt * 32 + lr];

  __syncthreads();   // all waves done READING s
  #pragma unroll
  for (int mt = 0; mt < 2; ++mt)
    #pragma unroll
    for (int nt = 0; nt < NT; ++nt)
      #pragma unroll
      for (int r = 0; r < 16; ++r) {
        float val = acc[mt][nt][r] + bv[nt];
        if (ACT) val = (val >= 0.f) ? val : 0.01f * val;
        const int row = mt * 32 + (r & 3) + 8 * (r >> 2) + 4 * lh;
        s[row * SMLP + (nbase + nt * 32 + lr)] = f2bf(val);
      }
  __syncthreads();   // writes visible before next layer reads
}

__global__ void __launch_bounds__(512, 4)
mlp_kernel(const unsigned short* __restrict__ Xg,
           const unsigned short* __restrict__ W0, const unsigned short* __restrict__ W1,
           const unsigned short* __restrict__ W2, const unsigned short* __restrict__ W3f,
           const float* __restrict__ b0, const float* __restrict__ b1,
           const float* __restrict__ b2, const float* __restrict__ b3,
           float* __restrict__ out) {
  __shared__ unsigned short s[64 * SMLP];   // 65 KB -> 2 blocks/CU

  // XCD swizzle: bid%8 = XCD; each XCD walks its 10 groups' 32 tiles.
  const int bid   = blockIdx.x;
  const int xcd   = bid & 7;
  const int local = bid >> 3;                // 0..319
  const int g     = xcd * 10 + (local >> 5);
  const int tile  = local & 31;
  const int m0    = tile * 64;

  const int tid  = threadIdx.x, lane = tid & 63;
  const int wn   = tid >> 6;                 // col strip 0..7

  // stage X tile [64][480]
  const unsigned short* Xs = Xg + ((size_t)g * BATCH + m0) * 480;
  for (int idx = tid; idx < 64 * 60; idx += 512) {
    int row = idx / 60, c = idx - row * 60;
    *(short8*)&s[row * SMLP + c * 8] = *(const short8*)(Xs + (size_t)row * 480 + c * 8);
  }
  __syncthreads();

  run_layer32<480, 512, true>(s, W0 + (size_t)g * 512 * 480, b0 + g * 512, wn, lane);
  run_layer32<512, 512, true>(s, W1 + (size_t)g * 512 * 512, b1 + g * 512, wn, lane);
  run_layer32<512, 256, true>(s, W2 + (size_t)g * 256 * 512, b2 + g * 256, wn, lane);

  // layer 4 via MFMA: [64x256] @ [256x16(pad 6)] ; waves 0-3 each own 16 rows.
  if (wn < 4) {
    const int lr = lane & 15, lh = lane >> 4;
    const unsigned short* aB4 = s + (wn * 16 + lr) * SMLP + lh * 8;
    const unsigned short* w3  = W3f + (size_t)g * 4096 + lane * 8;
    f32x4 a4 = (f32x4){0.f, 0.f, 0.f, 0.f};
    #pragma unroll
    for (int kk = 0; kk < 8; ++kk) {
      short8 av  = *(const short8*)(aB4 + kk * 32);
      short8 wv8 = *(const short8*)(w3 + (size_t)kk * 512);
      a4 = __builtin_amdgcn_mfma_f32_16x16x32_bf16(av, wv8, a4, 0, 0, 0);
    }
    const int col = lane & 15;
    if (col < 6) {
      const float bias3 = b3[g * 6 + col];
      #pragma unroll
      for (int r = 0; r < 4; ++r)
        out[((size_t)(m0 + wn * 16 + lh * 4 + r) * VJ + g) * 6 + col] = a4[r] + bias3;
    }
  }
}

// ---------------------------------------------------------------------------
extern "C" void kernel_launch(void* const* d_in, const int* in_sizes, int n_in,
                              void* d_out, int out_size, void* d_ws, size_t ws_size,
                              hipStream_t stream) {
  const float* qp   = (const float*)d_in[0];
  const float* pf   = (const float*)d_in[1];
  const float* Brff = (const float*)d_in[2];
  const float* v0 = (const float*)d_in[3];  const float* g0 = (const float*)d_in[4];  const float* b0 = (const float*)d_in[5];
  const float* v1 = (const float*)d_in[6];  const float* g1 = (const float*)d_in[7];  const float* b1 = (const float*)d_in[8];
  const float* v2 = (const float*)d_in[9];  const float* g2 = (const float*)d_in[10]; const float* b2 = (const float*)d_in[11];
  const float* v3 = (const float*)d_in[12]; const float* g3 = (const float*)d_in[13]; const float* b3 = (const float*)d_in[14];

  unsigned short* W0  = (unsigned short*)d_ws;                // 32x32 frag layout
  unsigned short* W1  = W0 + (size_t)VJ * HD2 * FS;
  unsigned short* W2  = W1 + (size_t)VJ * HD2 * HD2;
  unsigned short* W3f = W2 + (size_t)VJ * HD  * HD2;          // 16x16 frags, 6->16 pad
  unsigned short* Xg  = W3f + (size_t)VJ * 4096;              // [80][2048][480]

  // 3:2 interleave of 3280 weight-blocks and 2048 prep_x-blocks:
  // quintets = max(ceil(3280/3), ceil(2048/2)) = 1094 -> grid 5470.
  prep_all<<<dim3(5470), dim3(1024), 0, stream>>>(qp, pf, Brff,
                                                  v0, g0, v1, g1, v2, g2, v3, g3,
                                                  W0, W1, W2, W3f, Xg);
  mlp_kernel<<<dim3(VJ * 32), dim3(512), 0, stream>>>(Xg, W0, W1, W2, W3f,
                                                      b0, b1, b2, b3, (float*)d_out);
}